// Round 14
// 373.573 us; speedup vs baseline: 6.5871x; 1.0095x over previous
//
#include <hip/hip_runtime.h>
#include <hip/hip_bf16.h>
#include <math.h>

#define LL   512
#define DD   512
#define DII  1024
#define NST  16
#define BB   8
#define MM   4096
#define CHL  32
#define NCH  16
#define MB_  (1024*1024)
#define Q_(n) ((size_t)(n)*262144)   // quarter-MiB units

typedef __attribute__((ext_vector_type(8))) short bf16x8;
typedef __attribute__((ext_vector_type(4))) float f32x4;

// Fast HW-native activations (v_exp/v_log/v_rcp): rel err ~1e-6.
__device__ __forceinline__ float fast_rcp(float x){ return __builtin_amdgcn_rcpf(x); }
__device__ __forceinline__ float sigmoidf_(float x){ return fast_rcp(1.0f + __expf(-x)); }
__device__ __forceinline__ float siluf_(float x){ return x * sigmoidf_(x); }
__device__ __forceinline__ float softplusf_(float x){
    return fmaxf(x, 0.0f) + __logf(1.0f + __expf(-fabsf(x)));
}

__device__ __forceinline__ short f2bf(float f) {
    union { float f; unsigned u; } v; v.f = f;
    unsigned r = v.u + 0x7fffu + ((v.u >> 16) & 1u);
    return (short)(r >> 16);
}
__device__ __forceinline__ float bf2f(short s) {
    union { unsigned u; float f; } v; v.u = ((unsigned)(unsigned short)s) << 16;
    return v.f;
}
__device__ __forceinline__ bf16x8 pack_bf8(float4 v0, float4 v1) {
    union { bf16x8 v; short e[8]; } pk;
    pk.e[0]=f2bf(v0.x); pk.e[1]=f2bf(v0.y); pk.e[2]=f2bf(v0.z); pk.e[3]=f2bf(v0.w);
    pk.e[4]=f2bf(v1.x); pk.e[5]=f2bf(v1.y); pk.e[6]=f2bf(v1.z); pk.e[7]=f2bf(v1.w);
    return pk.v;
}
__device__ __forceinline__ void gl_lds16(const short* g, short* l) {
    __builtin_amdgcn_global_load_lds(
        (const __attribute__((address_space(1))) void*)g,
        (__attribute__((address_space(3))) void*)l, 16, 0, 0);
}

// ---------------------------------------------------------------------------
// Batched fp32 -> bf16 weight conversion (10 segments).
// ---------------------------------------------------------------------------
struct WcvtArgs { const float* s[10]; short* d[10]; int n[10]; };
__global__ void __launch_bounds__(256) wcvt_kernel(WcvtArgs a) {
    const int seg = blockIdx.y;
    const int i = (blockIdx.x*256 + threadIdx.x) * 8;
    if (i >= a.n[seg]) return;
    const float* s = a.s[seg] + i;
    float4 v0 = *(const float4*)s;
    float4 v1 = *(const float4*)(s + 4);
    int di = i;
    if (seg == 8) di = ((i >> 5) << 6) | (i & 31);   // pad K 32 -> 64
    *(bf16x8*)(a.d[seg] + di) = pack_bf8(v0, v1);
}

// wout [2][512][1024] f32 -> [2][1024][512] bf16
__global__ void __launch_bounds__(256) woutT_kernel(
    const float* __restrict__ wout, short* __restrict__ outT)
{
    __shared__ float sh[64][65];
    const int o0 = blockIdx.x << 6;
    const int j0 = blockIdx.y << 6;
    const int d  = blockIdx.z;
    const float* in = wout + (size_t)d*512*1024;
    short* out = outT + (size_t)d*1024*512;
    const int t = threadIdx.x;
    const int c4 = (t & 15) << 2;
    const int r  = t >> 4;
    #pragma unroll
    for (int i = 0; i < 4; i++) {
        int orow = r + i*16;
        float4 v = *(const float4*)(in + (size_t)(o0 + orow)*1024 + j0 + c4);
        sh[orow][c4+0]=v.x; sh[orow][c4+1]=v.y; sh[orow][c4+2]=v.z; sh[orow][c4+3]=v.w;
    }
    __syncthreads();
    #pragma unroll
    for (int i = 0; i < 4; i++) {
        int jr = r + i*16;
        short4 o;
        o.x = f2bf(sh[c4+0][jr]); o.y = f2bf(sh[c4+1][jr]);
        o.z = f2bf(sh[c4+2][jr]); o.w = f2bf(sh[c4+3][jr]);
        *(short4*)(out + (size_t)(j0 + jr)*512 + o0 + c4) = o;
    }
}

// ---------------------------------------------------------------------------
// gemm9 v2: 128x256 tile, BK=64, 512 thr = 8 waves (2Mx4N, wave tile 64x64),
// THREE-deep pipeline with counted vmcnt (12 = 2 tiles x 6 loads in flight):
// at 1 block/CU the 2-deep pipeline covered only ~1/3 of HBM latency; the
// third buffer covers ~2/3 (LDS 144 KB <= 160). T2 source-pre-swizzle +
// XCD swizzle as before.
// ---------------------------------------------------------------------------
__global__ void __launch_bounds__(512) gemm9_kernel(
    const short* __restrict__ A, int lda,
    const short* __restrict__ W, int ldw,
    const float* __restrict__ bias,
    short* __restrict__ outB, int ldc,
    int kLen, int act)
{
    __shared__ short As[3][128*64];
    __shared__ short Ws[3][256*64];

    const int tid = threadIdx.x, lane = tid & 63, wid = tid >> 6;

    int nwg = gridDim.x * gridDim.y;
    int flat = blockIdx.y * gridDim.x + blockIdx.x;
    if (!(nwg & 7)) { int cpx = nwg >> 3; flat = (flat & 7)*cpx + (flat >> 3); }
    const int bx = flat % gridDim.x, by = flat / gridDim.x;
    const int rowBase = by << 7;
    const int colBase = bx << 8;

    size_t asrc[2];
    #pragma unroll
    for (int rd = 0; rd < 2; rd++) {
        int id = rd*512 + tid, row = id >> 3, u = id & 7;
        asrc[rd] = (size_t)(rowBase + row)*lda + ((u ^ (row & 7)) << 3);
    }
    size_t wsrc[4];
    #pragma unroll
    for (int rd = 0; rd < 4; rd++) {
        int id = rd*512 + tid, row = id >> 3, u = id & 7;
        wsrc[rd] = (size_t)(colBase + row)*ldw + ((u ^ (row & 7)) << 3);
    }

    const int fr = lane & 15;
    const int swz0 = ((((lane >> 4)    ) ^ (lane & 7)) << 3);
    const int swz1 = ((((lane >> 4) | 4) ^ (lane & 7)) << 3);
    const int wm = (wid >> 2) * 64, wn = (wid & 3) * 64;

    f32x4 acc[4][4] = {};

    auto STAGE = [&](int buf, int k0) {
        #pragma unroll
        for (int rd = 0; rd < 2; rd++)
            gl_lds16(A + asrc[rd] + k0, &As[buf][(rd*512 + tid)*8]);
        #pragma unroll
        for (int rd = 0; rd < 4; rd++)
            gl_lds16(W + wsrc[rd] + k0, &Ws[buf][(rd*512 + tid)*8]);
    };

    const int nT = kLen >> 6;
    STAGE(0, 0);
    if (nT > 1) STAGE(1, 64);
    for (int t = 0; t < nT; ++t) {
        if (t + 2 < nT) {
            STAGE((t+2)%3, (t+2)*64);
            asm volatile("s_waitcnt vmcnt(12)" ::: "memory");
        } else if (t + 1 < nT) {
            asm volatile("s_waitcnt vmcnt(6)" ::: "memory");
        } else {
            asm volatile("s_waitcnt vmcnt(0)" ::: "memory");
        }
        __builtin_amdgcn_sched_barrier(0);
        __builtin_amdgcn_s_barrier();
        __builtin_amdgcn_sched_barrier(0);
        const int cur = t % 3;
        #pragma unroll
        for (int ks = 0; ks < 2; ks++) {
            const int so = ks ? swz1 : swz0;
            bf16x8 af[4], bfr[4];
            #pragma unroll
            for (int mi = 0; mi < 4; mi++)
                af[mi] = *(const bf16x8*)&As[cur][(wm + mi*16 + fr)*64 + so];
            #pragma unroll
            for (int ni = 0; ni < 4; ni++)
                bfr[ni] = *(const bf16x8*)&Ws[cur][(wn + ni*16 + fr)*64 + so];
            #pragma unroll
            for (int mi = 0; mi < 4; mi++)
                #pragma unroll
                for (int ni = 0; ni < 4; ni++)
                    acc[mi][ni] = __builtin_amdgcn_mfma_f32_16x16x32_bf16(af[mi], bfr[ni], acc[mi][ni], 0, 0, 0);
        }
        __builtin_amdgcn_sched_barrier(0);
        __builtin_amdgcn_s_barrier();
        __builtin_amdgcn_sched_barrier(0);
    }

    #pragma unroll
    for (int mi = 0; mi < 4; mi++)
        #pragma unroll
        for (int r = 0; r < 4; r++) {
            int orow = rowBase + wm + mi*16 + ((lane>>4)<<2) + r;
            #pragma unroll
            for (int ni = 0; ni < 4; ni++) {
                int gcol = colBase + wn + ni*16 + fr;
                float v = acc[mi][ni][r];
                if (bias) v += bias[gcol];
                if (act == 1) v = siluf_(v);
                outB[(size_t)orow*ldc + gcol] = f2bf(v);
            }
        }
}

// ---------------------------------------------------------------------------
// bf16 MFMA GEMM v8: 64xBN tile, BK=64, 4 waves, counted-vmcnt 2-deep
// pipeline, T2 source-pre-swizzle, XCD swizzle. Generalized batching.
// ---------------------------------------------------------------------------
template<int BN>
__global__ void __launch_bounds__(256) gemm3_kernel(
    const short* __restrict__ A, int lda,
    const short* __restrict__ W, int ldw,
    const float* __restrict__ bias,
    float* __restrict__ outF, short* __restrict__ outB, int ldc,
    int kLen, int kOff, int act, int actLim,
    size_t zA, size_t zW, int zB, size_t zO, int rowsPerW,
    float* __restrict__ partial, size_t pstride, int N)
{
    constexpr int WN = BN / 64;
    constexpr int WM = 4 / WN;
    constexpr int TM = 64 / WM;
    constexpr int FM = TM / 16;
    constexpr int WRW = BN / 32;

    __shared__ short As[2][64*64];
    __shared__ short Ws[2][BN*64];

    const int tid = threadIdx.x, lane = tid & 63, wid = tid >> 6;
    const int z = blockIdx.z;
    A += (size_t)z * zA;
    if (outF) outF += (size_t)z * zO;
    if (outB) outB += (size_t)z * zO;

    int nwg = gridDim.x * gridDim.y;
    int flat = blockIdx.y * gridDim.x + blockIdx.x;
    if (!(nwg & 7)) { int cpx = nwg >> 3; flat = (flat & 7)*cpx + (flat >> 3); }
    const int bx = flat % gridDim.x, by = flat / gridDim.x;

    const int rowBase = by << 6;
    const int colBase = bx * BN;
    const int kBase = z * kOff;

    const int dsel = rowsPerW ? (rowBase / rowsPerW) : z;
    W += (size_t)dsel * zW;
    if (bias) bias += (size_t)dsel * (size_t)zB;

    size_t asrc[2];
    #pragma unroll
    for (int rd = 0; rd < 2; rd++) {
        int id = rd*256 + tid, row = id >> 3, u = id & 7;
        asrc[rd] = (size_t)(rowBase + row)*lda + ((u ^ (row & 7)) << 3);
    }
    size_t wsrc[WRW];
    #pragma unroll
    for (int rd = 0; rd < WRW; rd++) {
        int id = rd*256 + tid, row = id >> 3, u = id & 7;
        wsrc[rd] = (size_t)(colBase + row)*ldw + ((u ^ (row & 7)) << 3);
    }

    const int fr = lane & 15;
    const int swz0 = ((((lane >> 4)    ) ^ (lane & 7)) << 3);
    const int swz1 = ((((lane >> 4) | 4) ^ (lane & 7)) << 3);
    const int wm = (wid / WN) * TM, wn = (wid % WN) * 64;

    f32x4 acc[FM][4] = {};

    auto STAGE = [&](int buf, int k0) {
        #pragma unroll
        for (int rd = 0; rd < 2; rd++)
            gl_lds16(A + asrc[rd] + k0, &As[buf][(rd*256 + tid)*8]);
        #pragma unroll
        for (int rd = 0; rd < WRW; rd++)
            gl_lds16(W + wsrc[rd] + k0, &Ws[buf][(rd*256 + tid)*8]);
    };

    const int nT = kLen >> 6;
    STAGE(0, kBase);
    int cur = 0;
    for (int t = 0; t < nT; ++t) {
        if (t + 1 < nT) {
            STAGE(cur ^ 1, kBase + (t+1)*64);
            asm volatile("s_waitcnt vmcnt(6)" ::: "memory");
        } else {
            asm volatile("s_waitcnt vmcnt(0)" ::: "memory");
        }
        __builtin_amdgcn_sched_barrier(0);
        __builtin_amdgcn_s_barrier();
        __builtin_amdgcn_sched_barrier(0);
        #pragma unroll
        for (int ks = 0; ks < 2; ks++) {
            const int so = ks ? swz1 : swz0;
            bf16x8 af[FM], bfr[4];
            #pragma unroll
            for (int mi = 0; mi < FM; mi++)
                af[mi] = *(const bf16x8*)&As[cur][(wm + mi*16 + fr)*64 + so];
            #pragma unroll
            for (int ni = 0; ni < 4; ni++)
                bfr[ni] = *(const bf16x8*)&Ws[cur][(wn + ni*16 + fr)*64 + so];
            #pragma unroll
            for (int mi = 0; mi < FM; mi++)
                #pragma unroll
                for (int ni = 0; ni < 4; ni++)
                    acc[mi][ni] = __builtin_amdgcn_mfma_f32_16x16x32_bf16(af[mi], bfr[ni], acc[mi][ni], 0, 0, 0);
        }
        __builtin_amdgcn_sched_barrier(0);
        __builtin_amdgcn_s_barrier();
        __builtin_amdgcn_sched_barrier(0);
        cur ^= 1;
    }

    if (partial) {
        float* pp = partial + (size_t)z * pstride;
        #pragma unroll
        for (int mi = 0; mi < FM; mi++)
            #pragma unroll
            for (int r = 0; r < 4; r++) {
                int orow = rowBase + wm + mi*16 + ((lane>>4)<<2) + r;
                #pragma unroll
                for (int ni = 0; ni < 4; ni++)
                    pp[(size_t)orow*N + colBase + wn + ni*16 + fr] = acc[mi][ni][r];
            }
    } else {
        #pragma unroll
        for (int mi = 0; mi < FM; mi++)
            #pragma unroll
            for (int r = 0; r < 4; r++) {
                int orow = rowBase + wm + mi*16 + ((lane>>4)<<2) + r;
                #pragma unroll
                for (int ni = 0; ni < 4; ni++) {
                    int gcol = colBase + wn + ni*16 + fr;
                    float v = acc[mi][ni][r];
                    if (bias) v += bias[gcol];
                    if (gcol < actLim) {
                        if (act == 1) v = siluf_(v);
                        else if (act == 2) v = softplusf_(v);
                    }
                    if (outF) outF[(size_t)orow*ldc + gcol] = v;
                    if (outB) outB[(size_t)orow*ldc + gcol] = f2bf(v);
                }
            }
    }
}

// ---------------------------------------------------------------------------
// Generic split-K reduce -> bf16 (xdb projection only).
// ---------------------------------------------------------------------------
__global__ void __launch_bounds__(256) reduce_kernel(
    const float* __restrict__ part, int S, size_t pstride, int N,
    short* __restrict__ outB, int ldc)
{
    const int i4 = blockIdx.x*256 + threadIdx.x;
    const int row = i4 / (N >> 2);
    const int c4  = (i4 - row*(N >> 2)) << 2;
    float4 s = *(const float4*)(part + (size_t)row*N + c4);
    for (int z = 1; z < S; z++) {
        float4 t = *(const float4*)(part + (size_t)z*pstride + (size_t)row*N + c4);
        s.x += t.x; s.y += t.y; s.z += t.z; s.w += t.w;
    }
    short4 o; o.x=f2bf(s.x); o.y=f2bf(s.y); o.z=f2bf(s.z); o.w=f2bf(s.w);
    *(short4*)(outB + (size_t)row*ldc + c4) = o;
}

// ---------------------------------------------------------------------------
// REDLN: sum S partials (N=512) + bias + resid*rscale -> h; optional fused
// LayerNorm -> bf16/f32.
// ---------------------------------------------------------------------------
__global__ void __launch_bounds__(128) redln_kernel(
    const float* __restrict__ part, int S,
    const float* __restrict__ bias,
    const float* __restrict__ resid, float rscale,
    float* __restrict__ houtF, short* __restrict__ houtB,
    const float* __restrict__ lng, const float* __restrict__ lnb2,
    float* __restrict__ lnoutF, short* __restrict__ lnoutB)
{
    const int row = blockIdx.x;
    const int t = threadIdx.x;
    const size_t pstride = (size_t)MM*512;
    float4 s = ((const float4*)(part + (size_t)row*512))[t];
    for (int z = 1; z < S; z++) {
        float4 v = ((const float4*)(part + z*pstride + (size_t)row*512))[t];
        s.x += v.x; s.y += v.y; s.z += v.z; s.w += v.w;
    }
    if (bias) { float4 b = ((const float4*)bias)[t]; s.x+=b.x; s.y+=b.y; s.z+=b.z; s.w+=b.w; }
    if (resid) {
        float4 r = ((const float4*)(resid + (size_t)row*512))[t];
        s.x = r.x + rscale*s.x; s.y = r.y + rscale*s.y;
        s.z = r.z + rscale*s.z; s.w = r.w + rscale*s.w;
    }
    if (houtF) ((float4*)(houtF + (size_t)row*512))[t] = s;
    if (houtB) {
        short4 o; o.x=f2bf(s.x); o.y=f2bf(s.y); o.z=f2bf(s.z); o.w=f2bf(s.w);
        *(short4*)(houtB + (size_t)row*512 + t*4) = o;
    }
    if (!lng) return;
    float sum = s.x+s.y+s.z+s.w;
    float sq  = s.x*s.x+s.y*s.y+s.z*s.z+s.w*s.w;
    #pragma unroll
    for (int off = 32; off >= 1; off >>= 1) {
        sum += __shfl_down(sum, off);
        sq  += __shfl_down(sq, off);
    }
    __shared__ float sh[4];
    if ((t & 63) == 0) { sh[(t>>6)*2] = sum; sh[(t>>6)*2+1] = sq; }
    __syncthreads();
    float mean = (sh[0]+sh[2]) * (1.0f/512.f);
    float var  = (sh[1]+sh[3]) * (1.0f/512.f) - mean*mean;
    float rstd = rsqrtf(var + 1e-5f);
    float4 gg = ((const float4*)lng)[t];
    float4 bb = ((const float4*)lnb2)[t];
    float4 o;
    o.x = (s.x-mean)*rstd*gg.x + bb.x;
    o.y = (s.y-mean)*rstd*gg.y + bb.y;
    o.z = (s.z-mean)*rstd*gg.z + bb.z;
    o.w = (s.w-mean)*rstd*gg.w + bb.w;
    if (lnoutF) ((float4*)(lnoutF + (size_t)row*512))[t] = o;
    if (lnoutB) {
        short4 ob; ob.x=f2bf(o.x); ob.y=f2bf(o.y); ob.z=f2bf(o.z); ob.w=f2bf(o.w);
        *(short4*)(lnoutB + (size_t)row*512 + t*4) = ob;
    }
}

// ---------------------------------------------------------------------------
// LayerNorm over 512 (pre-FFN1 only).
// ---------------------------------------------------------------------------
__global__ void __launch_bounds__(128) ln_kernel(
    const float* __restrict__ x, const float* __restrict__ g,
    const float* __restrict__ bta, short* __restrict__ outB)
{
    const int row = blockIdx.x;
    const int t = threadIdx.x;
    float4 v = ((const float4*)(x + (size_t)row*DD))[t];
    float s = v.x+v.y+v.z+v.w;
    float q = v.x*v.x+v.y*v.y+v.z*v.z+v.w*v.w;
    #pragma unroll
    for (int off = 32; off >= 1; off >>= 1) {
        s += __shfl_down(s, off);
        q += __shfl_down(q, off);
    }
    __shared__ float sh[4];
    if ((t & 63) == 0) { sh[(t>>6)*2] = s; sh[(t>>6)*2+1] = q; }
    __syncthreads();
    float mean = (sh[0]+sh[2]) * (1.0f/DD);
    float var  = (sh[1]+sh[3]) * (1.0f/DD) - mean*mean;
    float rstd = rsqrtf(var + 1e-5f);
    float4 gg = ((const float4*)g)[t];
    float4 bb = ((const float4*)bta)[t];
    short4 ob;
    ob.x = f2bf((v.x-mean)*rstd*gg.x + bb.x);
    ob.y = f2bf((v.y-mean)*rstd*gg.y + bb.y);
    ob.z = f2bf((v.z-mean)*rstd*gg.z + bb.z);
    ob.w = f2bf((v.w-mean)*rstd*gg.w + bb.w);
    *(short4*)(outB + (size_t)row*DD + t*4) = ob;
}

// ---------------------------------------------------------------------------
// Both-dir dwconv (K=4) + bias + SiLU, 4 channels/thread.
// ---------------------------------------------------------------------------
__global__ void __launch_bounds__(256) conv_both_kernel(
    const short* __restrict__ xz_all, const float* __restrict__ cw,
    const float* __restrict__ cb, short* __restrict__ xc_both)
{
    const int gid = blockIdx.x*256 + threadIdx.x;    // 2*MM*256 = 2^21
    const int c4  = (gid & 255) << 2;
    const int row = (gid >> 8) & (MM-1);
    const int dir = gid >> 20;
    const int l   = row & (LL-1);
    const short* base = xz_all + (size_t)(row - l)*4096 + dir*2048 + c4;
    float acc[4];
    #pragma unroll
    for (int j = 0; j < 4; j++) acc[j] = cb[dir*1024 + c4 + j];
    float wt[4][4];
    #pragma unroll
    for (int j = 0; j < 4; j++) {
        float4 w = *(const float4*)(cw + (size_t)dir*4096 + (c4 + j)*4);
        wt[j][0]=w.x; wt[j][1]=w.y; wt[j][2]=w.z; wt[j][3]=w.w;
    }
    #pragma unroll
    for (int t = 0; t < 4; t++) {
        int lt = dir ? (l + 3 - t) : (l - 3 + t);
        if (lt >= 0 && lt < LL) {
            short4 u = *(const short4*)(base + (size_t)lt*4096);
            acc[0] += wt[0][t]*bf2f(u.x);
            acc[1] += wt[1][t]*bf2f(u.y);
            acc[2] += wt[2][t]*bf2f(u.z);
            acc[3] += wt[3][t]*bf2f(u.w);
        }
    }
    short4 o;
    o.x = f2bf(siluf_(acc[0])); o.y = f2bf(siluf_(acc[1]));
    o.z = f2bf(siluf_(acc[2])); o.w = f2bf(siluf_(acc[3]));
    *(short4*)(xc_both + (size_t)dir*MM*1024 + (size_t)row*1024 + c4) = o;
}

// ---------------------------------------------------------------------------
// 3-pass scan, both dirs batched, CHL=32/NCH=16, exp-elim fast path.
// H buffer is bf16 (halves scan HBM traffic; 0.4% rel err on carried state,
// far inside the 0.03 -> 0.1 absmax budget).
// ---------------------------------------------------------------------------
__global__ void __launch_bounds__(256) scan_a_kernel(
    const short* __restrict__ dt_bf, const short* __restrict__ xc_both,
    const short* __restrict__ xdb_bf, const float* __restrict__ Alog,
    float* __restrict__ S_dt, short* __restrict__ H)
{
    const int bid = blockIdx.x;                // 1024
    const int dg  = bid & 3;
    const int c   = (bid >> 2) & (NCH-1);
    const int b   = (bid >> 6) & 7;
    const int dir = bid >> 9;
    const int d   = (dg << 8) + threadIdx.x;

    float Aexp[16];
    #pragma unroll
    for (int n = 0; n < 16; n++) Aexp[n] = -__expf(Alog[dir*16384 + d*16 + n]);
    const float A0 = Aexp[0];
    int fast = 1;
    #pragma unroll
    for (int n = 1; n < 16; n++)
        fast &= (fabsf(Aexp[n] - (float)(n+1)*A0) <= 1e-4f*fabsf(Aexp[n]) + 1e-6f);

    float h[16];
    #pragma unroll
    for (int n = 0; n < 16; n++) h[n] = 0.f;
    float S = 0.f;

    const size_t rbase = (size_t)b*LL + (size_t)c*CHL;
    const short* dtp = dt_bf + ((size_t)dir*MM + rbase)*1024 + d;
    const short* bcp = xdb_bf + ((size_t)dir*MM + rbase)*64 + 32;
    const short* xcp = xc_both + ((size_t)dir*MM + rbase)*1024 + d;

#define SCAN_A_BODY(FASTQ) \
    for (int i = 0; i < CHL; i++) { \
        int lp = dir ? (CHL-1-i) : i; \
        float dtv = bf2f(dtp[(size_t)lp*1024]); \
        float xcv = bf2f(xcp[(size_t)lp*1024]); \
        S += dtv; \
        float co = dtv*xcv; \
        union { bf16x8 v; short e[8]; } b0, b1; \
        b0.v = *(const bf16x8*)(bcp + (size_t)lp*64); \
        b1.v = *(const bf16x8*)(bcp + (size_t)lp*64 + 8); \
        float q[16]; \
        if (FASTQ) { \
            float p = __expf(dtv*A0); float qq = p; \
            _Pragma("unroll") for (int n = 0; n < 16; n++) { q[n] = qq; qq *= p; } \
        } else { \
            _Pragma("unroll") for (int n = 0; n < 16; n++) q[n] = __expf(dtv*Aexp[n]); \
        } \
        _Pragma("unroll") for (int n = 0; n < 16; n++) { \
            float Bv = bf2f(n < 8 ? b0.e[n] : b1.e[n & 7]); \
            h[n] = fmaf(q[n], h[n], co*Bv); \
        } \
    }
    if (fast) { SCAN_A_BODY(1) } else { SCAN_A_BODY(0) }
#undef SCAN_A_BODY

    S_dt[(((size_t)dir*BB + b)*NCH + c)*1024 + d] = S;
    const size_t hb = ((((size_t)dir*BB + b)*NCH + c)*16)*1024 + d;
    #pragma unroll
    for (int n = 0; n < 16; n++) H[hb + (size_t)n*1024] = f2bf(h[n]);
}

__global__ void __launch_bounds__(256) scan_b_kernel(
    const float* __restrict__ S_dt, short* H, const float* __restrict__ Alog)
{
    const int g = blockIdx.x*256 + threadIdx.x;  // 2*8*16*1024
    const int d = g & 1023;
    const int n = (g >> 10) & 15;
    const int b = (g >> 14) & 7;
    const int dir = g >> 17;
    const float Aexp = -__expf(Alog[dir*16384 + d*16 + n]);
    float h = 0.f;
    for (int ci = 0; ci < NCH; ci++) {
        int c = dir ? (NCH-1-ci) : ci;
        float S = S_dt[(((size_t)dir*BB + b)*NCH + c)*1024 + d];
        size_t i = ((((size_t)dir*BB + b)*NCH + c)*16 + n)*1024 + d;
        float q = __expf(Aexp*S);
        float hn = q*h + bf2f(H[i]);
        H[i] = f2bf(h);
        h = hn;
    }
}

__global__ void __launch_bounds__(256) scan_c_kernel(
    const short* __restrict__ dt_bf, short* xc_ys,
    const short* __restrict__ xdb_bf, const float* __restrict__ Alog,
    const short* __restrict__ H, const short* __restrict__ xz_all,
    const float* __restrict__ Dp)
{
    const int bid = blockIdx.x;                // 1024
    const int dg  = bid & 3;
    const int c   = (bid >> 2) & (NCH-1);
    const int b   = (bid >> 6) & 7;
    const int dir = bid >> 9;
    const int d   = (dg << 8) + threadIdx.x;

    float Aexp[16];
    #pragma unroll
    for (int n = 0; n < 16; n++) Aexp[n] = -__expf(Alog[dir*16384 + d*16 + n]);
    const float A0 = Aexp[0];
    int fast = 1;
    #pragma unroll
    for (int n = 1; n < 16; n++)
        fast &= (fabsf(Aexp[n] - (float)(n+1)*A0) <= 1e-4f*fabsf(Aexp[n]) + 1e-6f);
    const float Dpv = Dp[dir*1024 + d];

    float h[16];
    const size_t hb = ((((size_t)dir*BB + b)*NCH + c)*16)*1024 + d;
    #pragma unroll
    for (int n = 0; n < 16; n++) h[n] = bf2f(H[hb + (size_t)n*1024]);

    const size_t rbase = (size_t)b*LL + (size_t)c*CHL;
    const short* dtp = dt_bf + ((size_t)dir*MM + rbase)*1024 + d;
    const short* bcp = xdb_bf + ((size_t)dir*MM + rbase)*64 + 32;
    short*       xcp = xc_ys + ((size_t)dir*MM + rbase)*1024 + d;
    const short* zp  = xz_all + rbase*4096 + dir*2048 + 1024 + d;

#define SCAN_C_BODY(FASTQ) \
    for (int i = 0; i < CHL; i++) { \
        int lp = dir ? (CHL-1-i) : i; \
        float dtv = bf2f(dtp[(size_t)lp*1024]); \
        float xcv = bf2f(xcp[(size_t)lp*1024]); \
        float zv  = bf2f(zp[(size_t)lp*4096]); \
        float co = dtv*xcv; \
        union { bf16x8 v; short e[8]; } b0, b1, c0, c1; \
        b0.v = *(const bf16x8*)(bcp + (size_t)lp*64); \
        b1.v = *(const bf16x8*)(bcp + (size_t)lp*64 + 8); \
        c0.v = *(const bf16x8*)(bcp + (size_t)lp*64 + 16); \
        c1.v = *(const bf16x8*)(bcp + (size_t)lp*64 + 24); \
        float q[16]; \
        if (FASTQ) { \
            float p = __expf(dtv*A0); float qq = p; \
            _Pragma("unroll") for (int n = 0; n < 16; n++) { q[n] = qq; qq *= p; } \
        } else { \
            _Pragma("unroll") for (int n = 0; n < 16; n++) q[n] = __expf(dtv*Aexp[n]); \
        } \
        float y = 0.f; \
        _Pragma("unroll") for (int n = 0; n < 16; n++) { \
            float Bv = bf2f(n < 8 ? b0.e[n] : b1.e[n & 7]); \
            float Cv = bf2f(n < 8 ? c0.e[n] : c1.e[n & 7]); \
            h[n] = fmaf(q[n], h[n], co*Bv); \
            y = fmaf(Cv, h[n], y); \
        } \
        float out = (y + Dpv*xcv) * siluf_(zv); \
        xcp[(size_t)lp*1024] = f2bf(out); \
    }
    if (fast) { SCAN_C_BODY(1) } else { SCAN_C_BODY(0) }
#undef SCAN_C_BODY
}

// ---------------------------------------------------------------------------
// GLU + transpose to [b, c, l] f32.
// ---------------------------------------------------------------------------
__global__ void __launch_bounds__(256) glu_transpose_kernel(
    const float* __restrict__ pw1, float* __restrict__ out_t)
{
    __shared__ float sh[64][65];
    const int c0 = blockIdx.x << 6;
    const int l0 = blockIdx.y << 6;
    const int b  = blockIdx.z;
    const int t  = threadIdx.x;
    const int c4 = (t & 15) << 2;
    const int r  = t >> 4;
    #pragma unroll
    for (int i = 0; i < 4; i++) {
        int lrow = r + i*16;
        size_t row = (size_t)(b << 9) + l0 + lrow;
        float4 a = *(const float4*)(pw1 + row*1024 + c0 + c4);
        float4 g = *(const float4*)(pw1 + row*1024 + 512 + c0 + c4);
        sh[lrow][c4+0] = a.x * sigmoidf_(g.x);
        sh[lrow][c4+1] = a.y * sigmoidf_(g.y);
        sh[lrow][c4+2] = a.z * sigmoidf_(g.z);
        sh[lrow][c4+3] = a.w * sigmoidf_(g.w);
    }
    __syncthreads();
    #pragma unroll
    for (int i = 0; i < 4; i++) {
        int crow = r + i*16;
        float4 o;
        o.x = sh[c4+0][crow];
        o.y = sh[c4+1][crow];
        o.z = sh[c4+2][crow];
        o.w = sh[c4+3][crow];
        *(float4*)(out_t + ((size_t)(b << 9) + c0 + crow)*512 + l0 + c4) = o;
    }
}

// ---------------------------------------------------------------------------
// Channel-major fused 3x dwconv avg + BN + SiLU.
// ---------------------------------------------------------------------------
__global__ void __launch_bounds__(256) multiconv_t_kernel(
    const float* __restrict__ gin_t,
    const float* __restrict__ w15, const float* __restrict__ w31,
    const float* __restrict__ w63,
    const float* __restrict__ bn_g, const float* __restrict__ bn_b,
    const float* __restrict__ bn_m, const float* __restrict__ bn_v,
    float* __restrict__ out_t)
{
    __shared__ float sh[574];
    const int c = blockIdx.x & (DD-1);
    const int b = blockIdx.x >> 9;
    const int t = threadIdx.x;
    const float* rowp = gin_t + ((size_t)(b << 9) + c)*512;
    sh[31 + t]       = rowp[t];
    sh[31 + t + 256] = rowp[t + 256];
    if (t < 31) { sh[t] = 0.f; sh[543 + t] = 0.f; }
    __syncthreads();

    const float bnscale = rsqrtf(bn_v[c] + 1e-5f) * bn_g[c];
    const float bnm = bn_m[c], bnb = bn_b[c];
    float* outp = out_t + ((size_t)(b << 9) + c)*512;
    #pragma unroll
    for (int half = 0; half < 2; half++) {
        int l = t + half*256;
        float s63 = 0.f, s31 = 0.f, s15 = 0.f;
        #pragma unroll
        for (int k = 0; k < 63; k++) s63 += w63[c*63 + k] * sh[l + k];
        #pragma unroll
        for (int k = 0; k < 31; k++) s31 += w31[c*31 + k] * sh[l + 16 + k];
        #pragma unroll
        for (int k = 0; k < 15; k++) s15 += w15[c*15 + k] * sh[l + 24 + k];
        float m = (s15 + s31 + s63) * (1.0f/3.0f);
        m = (m - bnm) * bnscale + bnb;
        outp[l] = siluf_(m);
    }
}

// ---------------------------------------------------------------------------
// Transpose [b, c, l] -> [b, l, c], bf16 out.
// ---------------------------------------------------------------------------
__global__ void __launch_bounds__(256) transpose_bcl_kernel(
    const float* __restrict__ in_t, short* __restrict__ out)
{
    __shared__ float sh[64][65];
    const int l0 = blockIdx.x << 6;
    const int c0 = blockIdx.y << 6;
    const int b  = blockIdx.z;
    const int t  = threadIdx.x;
    const int l4 = (t & 15) << 2;
    const int r  = t >> 4;
    #pragma unroll
    for (int i = 0; i < 4; i++) {
        int crow = r + i*16;
        float4 v = *(const float4*)(in_t + ((size_t)(b << 9) + c0 + crow)*512 + l0 + l4);
        sh[crow][l4+0] = v.x; sh[crow][l4+1] = v.y;
        sh[crow][l4+2] = v.z; sh[crow][l4+3] = v.w;
    }
    __syncthreads();
    #pragma unroll
    for (int i = 0; i < 4; i++) {
        int lrow = r + i*16;
        short4 o;
        o.x = f2bf(sh[l4+0][lrow]);
        o.y = f2bf(sh[l4+1][lrow]);
        o.z = f2bf(sh[l4+2][lrow]);
        o.w = f2bf(sh[l4+3][lrow]);
        *(short4*)(out + ((size_t)(b << 9) + l0 + lrow)*512 + c0 + l4) = o;
    }
}

// ---------------------------------------------------------------------------
extern "C" void kernel_launch(void* const* d_in, const int* in_sizes, int n_in,
                              void* d_out, int out_size, void* d_ws, size_t ws_size,
                              hipStream_t stream)
{
    const float* x        = (const float*)d_in[0];
    const float* ff1_ln_g = (const float*)d_in[1];
    const float* ff1_ln_b = (const float*)d_in[2];
    const float* ff1_w1   = (const float*)d_in[3];
    const float* ff1_b1   = (const float*)d_in[4];
    const float* ff1_w2   = (const float*)d_in[5];
    const float* ff1_b2   = (const float*)d_in[6];
    const float* ff2_ln_g = (const float*)d_in[7];
    const float* ff2_ln_b = (const float*)d_in[8];
    const float* ff2_w1   = (const float*)d_in[9];
    const float* ff2_b1   = (const float*)d_in[10];
    const float* ff2_w2   = (const float*)d_in[11];
    const float* ff2_b2   = (const float*)d_in[12];
    const float* m_win    = (const float*)d_in[13];
    const float* m_convw  = (const float*)d_in[14];
    const float* m_convb  = (const float*)d_in[15];
    const float* m_wx     = (const float*)d_in[16];
    const float* m_wdt    = (const float*)d_in[17];
    const float* m_bdt    = (const float*)d_in[18];
    const float* m_Alog   = (const float*)d_in[19];
    const float* m_Dp     = (const float*)d_in[20];
    const float* m_wout   = (const float*)d_in[21];
    const float* bi_wo    = (const float*)d_in[22];
    const float* bi_bo    = (const float*)d_in[23];
    const float* cv_ln_g  = (const float*)d_in[24];
    const float* cv_ln_b  = (const float*)d_in[25];
    const float* cv_pw1_w = (const float*)d_in[26];
    const float* cv_pw1_b = (const float*)d_in[27];
    const float* cv_dw15  = (const float*)d_in[28];
    const float* cv_dw31  = (const float*)d_in[29];
    const float* cv_dw63  = (const float*)d_in[30];
    const float* cv_bn_g  = (const float*)d_in[31];
    const float* cv_bn_b  = (const float*)d_in[32];
    const float* cv_bn_m  = (const float*)d_in[33];
    const float* cv_bn_v  = (const float*)d_in[34];
    const float* cv_pw2_w = (const float*)d_in[35];
    const float* cv_pw2_b = (const float*)d_in[36];
    const float* ln_g     = (const float*)d_in[37];
    const float* ln_b     = (const float*)d_in[38];

    // ---- Workspace (quarter-MiB offsets), total 105.5 MiB ----
    char* wsb = (char*)d_ws;
    float* h        = (float*)(wsb + Q_(0));     // 8 MB
    short* h_bf     = (short*)(wsb + Q_(32));    // 4 MB
    short* lnb_bf   = (short*)(wsb + Q_(48));    // 4 MB
    short* w_ff1w1  = (short*)(wsb + Q_(64));
    short* w_ff1w2  = (short*)(wsb + Q_(72));
    short* w_ff2w1  = (short*)(wsb + Q_(80));
    short* w_ff2w2  = (short*)(wsb + Q_(88));
    short* w_win    = (short*)(wsb + Q_(96));    // [4096,512] 4 MB
    short* w_pw1    = (short*)(wsb + Q_(112));
    short* w_pw2    = (short*)(wsb + Q_(116));
    short* w_Wc     = (short*)(wsb + Q_(118));   // [2][512][1024] 2 MB
    short* w_wdtp   = (short*)(wsb + Q_(126));   // [2][1024][64] 0.25 MB
    short* w_wx     = (short*)(wsb + Q_(127));   // [2][64][1024] 0.25 MB
    float* part     = (float*)(wsb + Q_(128));   // 16 MB partials / pw1out
    short* Hbuf     = (short*)(wsb + Q_(128));   // 8 MB bf16 scan H overlay
    float* S_dt     = (float*)(wsb + Q_(192));   // 1 MB
    short* xz_all   = (short*)(wsb + Q_(226));   // [MM,4096] 16 MB
    short* woutT_ov = (short*)(wsb + Q_(226));   // prep overlay 2 MB
    short* biwo_ov  = (short*)(wsb + Q_(234));   // prep overlay 1 MB
    float* glu_t    = (float*)(wsb + Q_(226));   // ConvMod overlay 8 MB
    short* xc_both  = (short*)(wsb + Q_(290));   // [2][MM,1024] 16 MB
    short* hid_bf   = (short*)(wsb + Q_(290));   // FFN overlay [MM,2048] 8 MB
    short* dt_bf    = (short*)(wsb + Q_(354));   // [2][MM,1024] 16 MB
    float* mconv_o  = (float*)(wsb + Q_(354));   // ConvMod overlay 8 MB
    short* xdb_bf   = (short*)(wsb + Q_(418));   // [2][MM,64] 1 MB -> ends 422

    if (ws_size < Q_(422)) return;

    // ---- Prep ----
    hipMemsetAsync(w_wdtp, 0, (size_t)2*1024*64*2, stream);
    WcvtArgs wa;
    wa.s[0]=ff1_w1;   wa.d[0]=w_ff1w1; wa.n[0]=1048576;
    wa.s[1]=ff1_w2;   wa.d[1]=w_ff1w2; wa.n[1]=1048576;
    wa.s[2]=ff2_w1;   wa.d[2]=w_ff2w1; wa.n[2]=1048576;
    wa.s[3]=ff2_w2;   wa.d[3]=w_ff2w2; wa.n[3]=1048576;
    wa.s[4]=m_win;    wa.d[4]=w_win;   wa.n[4]=2097152;
    wa.s[5]=bi_wo;    wa.d[5]=biwo_ov; wa.n[5]=524288;
    wa.s[6]=cv_pw1_w; wa.d[6]=w_pw1;   wa.n[6]=524288;
    wa.s[7]=cv_pw2_w; wa.d[7]=w_pw2;   wa.n[7]=262144;
    wa.s[8]=m_wdt;    wa.d[8]=w_wdtp;  wa.n[8]=65536;   // pad K 32->64
    wa.s[9]=m_wx;     wa.d[9]=w_wx;    wa.n[9]=131072;
    wcvt_kernel<<<dim3(1024,10), 256, 0, stream>>>(wa);
    woutT_kernel<<<dim3(8,16,2), 256, 0, stream>>>(m_wout, woutT_ov);

    auto G = [&](const short* A, int lda, const short* W, int ldw,
                 const float* bias, float* oF, short* oB, int ldc,
                 int M, int N, int nz, int kLen, int kOff,
                 size_t zA, size_t zW, int zB, size_t zO, int rowsPerW,
                 int act, int actLim, float* prt) {
        dim3 g(N/128, M/64, nz);
        gemm3_kernel<128><<<g, 256, 0, stream>>>(A, lda, W, ldw, bias, oF, oB, ldc,
            kLen, kOff, act, actLim, zA, zW, zB, zO, rowsPerW,
            prt, (size_t)M*N, N);
    };

    // Wc = biwo_half @ woutT -> [2][512][1024] bf16 (batched z=dir)
    G(biwo_ov, 1024, woutT_ov, 512, nullptr, nullptr, w_Wc, 1024,
      512, 1024, 2, 512, 0, 512, 524288, 0, 524288, 0, 0, 0, nullptr);

    // ---- FFN1 ----
    ln_kernel<<<MM, 128, 0, stream>>>(x, ff1_ln_g, ff1_ln_b, lnb_bf);
    gemm9_kernel<<<dim3(8, 32), 512, 0, stream>>>(lnb_bf, 512, w_ff1w1, 512,
        ff1_b1, hid_bf, 2048, 512, 1);
    G(hid_bf, 2048, w_ff1w2, 2048, nullptr, nullptr, nullptr, 0,
      MM, 512, 2, 1024, 1024, 0, 0, 0, 0, 0, 0, 0, part);
    redln_kernel<<<MM, 128, 0, stream>>>(part, 2, ff1_b2, x, 0.5f,
        h, h_bf, nullptr, nullptr, nullptr, nullptr);

    // ---- BiMamba ----
    gemm9_kernel<<<dim3(16, 32), 512, 0, stream>>>(h_bf, 512, w_win, 512,
        nullptr, xz_all, 4096, 512, 0);
    conv_both_kernel<<<8192, 256, 0, stream>>>(xz_all, m_convw, m_convb, xc_both);
    // xdb = xc @ wx^T : M=8192 (both dirs), N=64, split-K 4, W by row-dir
    {
        dim3 g(1, 128, 4);
        gemm3_kernel<64><<<g, 256, 0, stream>>>(xc_both, 1024, w_wx, 1024,
            nullptr, nullptr, nullptr, 0, 256, 256, 0, 0,
            0, 65536, 0, 0, 4096, part, (size_t)8192*64, 64);
    }
    reduce_kernel<<<512, 256, 0, stream>>>(part, 4, (size_t)8192*64, 64, xdb_bf, 64);
    // dt = softplus(xdb @ wdt_pad^T + bdt)
    G(xdb_bf, 64, w_wdtp, 64, m_bdt, nullptr, dt_bf, 1024,
      8192, 1024, 1, 64, 0, 0, 65536, 1024, 0, 4096, 2, 1024, nullptr);
    // 3-pass scan + fused ycombine (ys overwrites xc_both)
    scan_a_kernel<<<1024, 256, 0, stream>>>(dt_bf, xc_both, xdb_bf, m_Alog, S_dt, Hbuf);
    scan_b_kernel<<<1024, 256, 0, stream>>>(S_dt, Hbuf, m_Alog);
    scan_c_kernel<<<1024, 256, 0, stream>>>(dt_bf, xc_both, xdb_bf, m_Alog, Hbuf,
                                            xz_all, m_Dp);
    // h += ys0@Wc0 + ys1@Wc1 + bi_bo ; fused cv-LN
    G(xc_both, 1024, w_Wc, 1024, nullptr, nullptr, nullptr, 0,
      MM, 512, 2, 1024, 0, (size_t)MM*1024, 524288, 0, 0, 0, 0, 0, part);
    redln_kernel<<<MM, 128, 0, stream>>>(part, 2, bi_bo, h, 1.0f,
        h, nullptr, cv_ln_g, cv_ln_b, nullptr, lnb_bf);

    // ---- ConvMod ----
    G(lnb_bf, 512, w_pw1, 512, cv_pw1_b, part, nullptr, 1024,
      MM, 1024, 1, 512, 0, 0, 0, 0, 0, 0, 0, 0, nullptr);
    glu_transpose_kernel<<<dim3(8,8,8), 256, 0, stream>>>(part, glu_t);
    multiconv_t_kernel<<<BB*DD, 256, 0, stream>>>(glu_t,
        cv_dw15, cv_dw31, cv_dw63, cv_bn_g, cv_bn_b, cv_bn_m, cv_bn_v, mconv_o);
    transpose_bcl_kernel<<<dim3(8,8,8), 256, 0, stream>>>(mconv_o, lnb_bf);
    G(lnb_bf, 512, w_pw2, 512, nullptr, nullptr, nullptr, 0,
      MM, 512, 2, 256, 256, 0, 0, 0, 0, 0, 0, 0, part);
    redln_kernel<<<MM, 128, 0, stream>>>(part, 2, cv_pw2_b, h, 1.0f,
        h, nullptr, ff2_ln_g, ff2_ln_b, nullptr, lnb_bf);

    // ---- FFN2 ----
    gemm9_kernel<<<dim3(8, 32), 512, 0, stream>>>(lnb_bf, 512, w_ff2w1, 512,
        ff2_b1, hid_bf, 2048, 512, 1);
    G(hid_bf, 2048, w_ff2w2, 2048, nullptr, nullptr, nullptr, 0,
      MM, 512, 2, 1024, 1024, 0, 0, 0, 0, 0, 0, 0, part);
    // final: h = h + 0.5*v, then LN -> d_out (f32)
    redln_kernel<<<MM, 128, 0, stream>>>(part, 2, ff2_b2, h, 0.5f,
        nullptr, nullptr, ln_g, ln_b, (float*)d_out, nullptr);
}